// Round 6
// baseline (163.761 us; speedup 1.0000x reference)
//
#include <hip/hip_runtime.h>
#include <math.h>
#include <stdint.h>

#define BN 4
#define TN 4096
#define EN 1024
#define HN 64
#define BT (BN*TN)

typedef __attribute__((ext_vector_type(8))) short   short8;   // 8 bf16 MFMA frag
typedef __attribute__((ext_vector_type(4))) float   f32x4;    // MFMA acc
typedef __attribute__((ext_vector_type(4))) unsigned short us4;
typedef __attribute__((ext_vector_type(8))) unsigned short us8;

// fp32 -> bf16 RNE
__device__ __forceinline__ unsigned short f2b(float f) {
    union { float f; uint32_t u; } v; v.f = f;
    uint32_t u = v.u;
    return (unsigned short)((u + 0x7FFFu + ((u >> 16) & 1u)) >> 16);
}

__device__ __forceinline__ float fexp2(float x) {
#if __has_builtin(__builtin_amdgcn_exp2f)
    return __builtin_amdgcn_exp2f(x);
#else
    return exp2f(x);
#endif
}

// ---------------------------------------------------------------------------
// W -> bf16. Rows 0-63: Wq scaled by log2(e)/32 (softmax in exp2 domain).
// Rows 64-127: Wk. Rows 128-191: Wv.
// ---------------------------------------------------------------------------
__global__ __launch_bounds__(256)
void wconv(const float* __restrict__ Wq, const float* __restrict__ Wk,
           const float* __restrict__ Wv, unsigned short* __restrict__ W16) {
    const int row = blockIdx.x;
    const int t = threadIdx.x;
    const float* src;
    float sc = 1.0f;
    if (row < 64)       { src = Wq + (size_t)row * EN; sc = 0.045084220f; }
    else if (row < 128) { src = Wk + (size_t)(row - 64) * EN; }
    else                { src = Wv + (size_t)(row - 128) * EN; }
    float4 v = *(const float4*)(src + t * 4);
    us4 p;
    p[0] = f2b(v.x * sc); p[1] = f2b(v.y * sc);
    p[2] = f2b(v.z * sc); p[3] = f2b(v.w * sc);
    *(us4*)&W16[(size_t)row * EN + t * 4] = p;
}

// ---------------------------------------------------------------------------
// QKV projection GEMM: C[16384][192] = emb * W16^T, bf16 MFMA.
// 512 threads = 8 waves (2M x 4N), tile 64 x 192, K-step 64, double-buffered
// LDS with TWO-step-ahead register prefetch (covers ~900cy HBM latency).
// Q,K written [wsel][r][d]; V written transposed [b][d][t].
// ---------------------------------------------------------------------------
__global__ __launch_bounds__(512, 2)
void qkv_gemm(const float* __restrict__ emb, const unsigned short* __restrict__ W16,
              unsigned short* __restrict__ QK, unsigned short* __restrict__ VT) {
    __shared__ __align__(16) unsigned short A_lds[2][64][72];
    __shared__ __align__(16) unsigned short B_lds[2][192][72];

    const int tid = threadIdx.x;
    const int wid = tid >> 6, lane = tid & 63;
    const int c = lane & 15, g = lane >> 4;
    const int wm = wid & 1, wn = wid >> 1;          // 2M x 4N waves
    const int r0 = blockIdx.x * 64;
    const int ar = tid >> 3, ach = tid & 7;         // A staging map

    const int br0 = tid >> 3,           bch0 = tid & 7;
    const int br1 = (tid + 512) >> 3,   bch1 = bch0;
    const int br2 = (tid + 1024) >> 3,  bch2 = bch0;

    const f32x4 fzero = {0.f, 0.f, 0.f, 0.f};
    f32x4 acc[2][3];
    #pragma unroll
    for (int i = 0; i < 2; ++i)
        #pragma unroll
        for (int j = 0; j < 3; ++j) acc[i][j] = fzero;

    // two register prefetch banks
    float4 pa0[2], pa1[2];
    us8 pb0[2], pb1[2], pb2[2];

    // ---- prologue: issue loads for steps 0 and 1
    #pragma unroll
    for (int t = 0; t < 2; ++t) {
        const int k0 = t * 64;
        pa0[t] = *(const float4*)&emb[(size_t)(r0 + ar) * EN + k0 + ach * 8];
        pa1[t] = *(const float4*)&emb[(size_t)(r0 + ar) * EN + k0 + ach * 8 + 4];
        pb0[t] = *(const us8*)&W16[(size_t)br0 * EN + k0 + bch0 * 8];
        pb1[t] = *(const us8*)&W16[(size_t)br1 * EN + k0 + bch1 * 8];
        pb2[t] = *(const us8*)&W16[(size_t)br2 * EN + k0 + bch2 * 8];
    }
    // write step 0 (bank 0) into LDS buf 0
    {
        us8 ap;
        ap[0] = f2b(pa0[0].x); ap[1] = f2b(pa0[0].y); ap[2] = f2b(pa0[0].z); ap[3] = f2b(pa0[0].w);
        ap[4] = f2b(pa1[0].x); ap[5] = f2b(pa1[0].y); ap[6] = f2b(pa1[0].z); ap[7] = f2b(pa1[0].w);
        *(us8*)&A_lds[0][ar][ach * 8] = ap;
        *(us8*)&B_lds[0][br0][bch0 * 8] = pb0[0];
        *(us8*)&B_lds[0][br1][bch1 * 8] = pb1[0];
        *(us8*)&B_lds[0][br2][bch2 * 8] = pb2[0];
    }
    __syncthreads();

    #pragma unroll 2
    for (int t = 0; t < 16; ++t) {
        const int cur = t & 1;    // static after unroll-2
        // issue loads for step t+2 into bank[cur] (its old data already in LDS)
        if (t + 2 < 16) {
            const int kn = (t + 2) * 64;
            pa0[cur] = *(const float4*)&emb[(size_t)(r0 + ar) * EN + kn + ach * 8];
            pa1[cur] = *(const float4*)&emb[(size_t)(r0 + ar) * EN + kn + ach * 8 + 4];
            pb0[cur] = *(const us8*)&W16[(size_t)br0 * EN + kn + bch0 * 8];
            pb1[cur] = *(const us8*)&W16[(size_t)br1 * EN + kn + bch1 * 8];
            pb2[cur] = *(const us8*)&W16[(size_t)br2 * EN + kn + bch2 * 8];
        }

        // compute from LDS[cur]
        short8 af[2][2], bf[3][2];
        #pragma unroll
        for (int rt = 0; rt < 2; ++rt)
            #pragma unroll
            for (int ks = 0; ks < 2; ++ks)
                af[rt][ks] = *(const short8*)&A_lds[cur][32 * wm + 16 * rt + c][32 * ks + 8 * g];
        #pragma unroll
        for (int nt = 0; nt < 3; ++nt)
            #pragma unroll
            for (int ks = 0; ks < 2; ++ks)
                bf[nt][ks] = *(const short8*)&B_lds[cur][48 * wn + 16 * nt + c][32 * ks + 8 * g];
        #pragma unroll
        for (int ks = 0; ks < 2; ++ks)
            #pragma unroll
            for (int rt = 0; rt < 2; ++rt)
                #pragma unroll
                for (int nt = 0; nt < 3; ++nt)
                    acc[rt][nt] = __builtin_amdgcn_mfma_f32_16x16x32_bf16(
                        af[rt][ks], bf[nt][ks], acc[rt][nt], 0, 0, 0);

        // write bank[(t+1)&1] (holding step t+1, issued one step ago) to LDS
        if (t + 1 < 16) {
            const int nb = cur ^ 1;
            us8 ap;
            ap[0] = f2b(pa0[nb].x); ap[1] = f2b(pa0[nb].y); ap[2] = f2b(pa0[nb].z); ap[3] = f2b(pa0[nb].w);
            ap[4] = f2b(pa1[nb].x); ap[5] = f2b(pa1[nb].y); ap[6] = f2b(pa1[nb].z); ap[7] = f2b(pa1[nb].w);
            *(us8*)&A_lds[nb][ar][ach * 8] = ap;
            *(us8*)&B_lds[nb][br0][bch0 * 8] = pb0[nb];
            *(us8*)&B_lds[nb][br1][bch1 * 8] = pb1[nb];
            *(us8*)&B_lds[nb][br2][bch2 * 8] = pb2[nb];
        }
        __syncthreads();
    }

    // epilogue: D row = 4g+j (A side), col = c (B side)  [proven layout]
    #pragma unroll
    for (int rt = 0; rt < 2; ++rt) {
        #pragma unroll
        for (int nt = 0; nt < 3; ++nt) {
            const int n = 48 * wn + 16 * nt + c;
            const int wsel = n >> 6;
            const int d = n & 63;
            const int rbase = r0 + 32 * wm + 16 * rt + 4 * g;
            if (wsel < 2) {
                #pragma unroll
                for (int j = 0; j < 4; ++j)
                    QK[(size_t)wsel * BT * HN + (size_t)(rbase + j) * HN + d] =
                        f2b(acc[rt][nt][j]);
            } else {
                const int bb = rbase >> 12;
                const int tt = rbase & 4095;
                us4 p;
                #pragma unroll
                for (int j = 0; j < 4; ++j) p[j] = f2b(acc[rt][nt][j]);
                *(us4*)&VT[(size_t)bb * HN * TN + (size_t)d * TN + tt] = p;
            }
        }
    }
}

// ---------------------------------------------------------------------------
// Flash attention, bf16 MFMA, causal. Q-tile 32, grid 512, 512 threads =
// 8 waves; wave w owns KV-tiles jt = w, w+8, ... independently (no barriers
// in main loop). K/V frags read DIRECTLY from global (L2-resident; K is
// row-major [t][d], V pre-transposed [b][d][t] -> both frag-contiguous).
// Only P round-trips through a per-wave LDS slot. Merge (m,l,O) at end.
// ---------------------------------------------------------------------------
#define NW 8

__global__ __launch_bounds__(512, 4)
void attn(const unsigned short* __restrict__ QK,
          const unsigned short* __restrict__ VT, float* __restrict__ out) {
    // union region: P slots (8 x 32 x 72 us = 36.9KB) then reused as
    // f32 Oslab (8 x 32 x 65 = 66.6KB)
    __shared__ __align__(16) unsigned char SLAB[NW * 32 * 65 * 4];
    __shared__ __align__(16) float MLm[NW][32];
    __shared__ __align__(16) float MLl[NW][32];
    __shared__ __align__(16) float ML2m[32];
    __shared__ __align__(16) float ML2l[32];

    const int tid = threadIdx.x;
    const int w = tid >> 6, lane = tid & 63, c = lane & 15, g = lane >> 4;
    const int bid = blockIdx.x;
    const int b = bid & 3;
    const int qt = (TN / 32 - 1) - (bid >> 2);   // heavy q-tiles first

    const unsigned short* Qg = QK + ((size_t)b * TN + (size_t)qt * 32) * HN;
    const unsigned short* Kg = QK + (size_t)BT * HN + (size_t)b * TN * HN;
    const unsigned short* Vg = VT + (size_t)b * HN * TN;

    unsigned short* Pw = (unsigned short*)SLAB + (size_t)w * 32 * 72;

    // Q fragments straight from global (L2/L3-resident)
    short8 bq[2][2];
    #pragma unroll
    for (int ct = 0; ct < 2; ++ct)
        #pragma unroll
        for (int ks = 0; ks < 2; ++ks)
            bq[ct][ks] = *(const short8*)&Qg[(size_t)(16 * ct + c) * HN + 32 * ks + 8 * g];

    const f32x4 fzero = {0.f, 0.f, 0.f, 0.f};
    f32x4 o[2][4];
    #pragma unroll
    for (int i = 0; i < 2; ++i)
        #pragma unroll
        for (int j = 0; j < 4; ++j) o[i][j] = fzero;
    float m[2] = {-INFINITY, -INFINITY};
    float l[2] = {0.f, 0.f};

    const int jmax = qt >> 1;

    for (int jt = w; jt <= jmax; jt += NW) {
        // ---- S^T[64k][32q] = K . Q^T ; K frags direct from global
        f32x4 st[4][2];
        #pragma unroll
        for (int kt = 0; kt < 4; ++kt)
            #pragma unroll
            for (int ct = 0; ct < 2; ++ct) st[kt][ct] = fzero;
        #pragma unroll
        for (int kt = 0; kt < 4; ++kt) {
            #pragma unroll
            for (int ks = 0; ks < 2; ++ks) {
                short8 ak = *(const short8*)
                    &Kg[((size_t)jt * 64 + 16 * kt + c) * HN + 32 * ks + 8 * g];
                #pragma unroll
                for (int ct = 0; ct < 2; ++ct)
                    st[kt][ct] = __builtin_amdgcn_mfma_f32_16x16x32_bf16(
                        ak, bq[ct][ks], st[kt][ct], 0, 0, 0);
            }
        }

        // ---- causal mask (only the last tile crosses the diagonal)
        if (jt == jmax) {
            const int koff = jt * 64 - qt * 32;
            #pragma unroll
            for (int kt = 0; kt < 4; ++kt)
                #pragma unroll
                for (int ct = 0; ct < 2; ++ct)
                    #pragma unroll
                    for (int j = 0; j < 4; ++j)
                        if (16 * kt + 4 * g + j + koff > 16 * ct + c)
                            st[kt][ct][j] = -INFINITY;
        }

        // ---- online softmax (exp2 domain), per q = 16ct + c
        #pragma unroll
        for (int ct = 0; ct < 2; ++ct) {
            float pmax = -INFINITY;
            #pragma unroll
            for (int kt = 0; kt < 4; ++kt)
                #pragma unroll
                for (int j = 0; j < 4; ++j) pmax = fmaxf(pmax, st[kt][ct][j]);
            pmax = fmaxf(pmax, __shfl_xor(pmax, 16));
            pmax = fmaxf(pmax, __shfl_xor(pmax, 32));
            const float mn = fmaxf(m[ct], pmax);
            const float alpha = fexp2(m[ct] - mn);
            float ls = 0.f;
            #pragma unroll
            for (int kt = 0; kt < 4; ++kt)
                #pragma unroll
                for (int j = 0; j < 4; ++j) {
                    float p = fexp2(st[kt][ct][j] - mn);
                    st[kt][ct][j] = p;
                    ls += p;
                }
            ls += __shfl_xor(ls, 16);
            ls += __shfl_xor(ls, 32);
            l[ct] = l[ct] * alpha + ls;
            m[ct] = mn;

            float a4[4];
            #pragma unroll
            for (int j = 0; j < 4; ++j) a4[j] = __shfl(alpha, 4 * g + j);
            #pragma unroll
            for (int dt = 0; dt < 4; ++dt)
                #pragma unroll
                for (int j = 0; j < 4; ++j) o[ct][dt][j] *= a4[j];
        }

        // ---- write P[32q][64k] bf16 into per-wave LDS slot (wave-local)
        #pragma unroll
        for (int kt = 0; kt < 4; ++kt)
            #pragma unroll
            for (int ct = 0; ct < 2; ++ct) {
                us4 p;
                #pragma unroll
                for (int j = 0; j < 4; ++j) p[j] = f2b(st[kt][ct][j]);
                *(us4*)&Pw[(16 * ct + c) * 72 + 16 * kt + 4 * g] = p;
            }

        // ---- O += P . V ; V frags direct from global (pre-transposed)
        #pragma unroll
        for (int ks = 0; ks < 2; ++ks) {
            short8 pa[2];
            #pragma unroll
            for (int qp = 0; qp < 2; ++qp)
                pa[qp] = *(const short8*)&Pw[(16 * qp + c) * 72 + 32 * ks + 8 * g];
            #pragma unroll
            for (int dt = 0; dt < 4; ++dt) {
                short8 bv = *(const short8*)
                    &Vg[(size_t)(16 * dt + c) * TN + jt * 64 + 32 * ks + 8 * g];
                #pragma unroll
                for (int qp = 0; qp < 2; ++qp)
                    o[qp][dt] = __builtin_amdgcn_mfma_f32_16x16x32_bf16(
                        pa[qp], bv, o[qp][dt], 0, 0, 0);
            }
        }
    }

    // ---- publish per-wave m,l
    if (g == 0) {
        MLm[w][c]      = m[0];  MLl[w][c]      = l[0];
        MLm[w][c + 16] = m[1];  MLl[w][c + 16] = l[1];
    }
    __syncthreads();

    // ---- combine m,l across waves
    if (tid < 32) {
        const int q = tid;
        float M = MLm[0][q];
        #pragma unroll
        for (int s = 1; s < NW; ++s) M = fmaxf(M, MLm[s][q]);
        float L = 0.f;
        #pragma unroll
        for (int s = 0; s < NW; ++s) L += MLl[s][q] * fexp2(MLm[s][q] - M);
        ML2m[q] = M;
        ML2l[q] = L;
    }
    __syncthreads();   // also ensures ALL waves are past the main loop

    // ---- scale own O and dump to per-wave f32 slot (aliases P region)
    float* Oslab = (float*)SLAB;
    float* Ow = Oslab + (size_t)w * (32 * 65);
    #pragma unroll
    for (int qp = 0; qp < 2; ++qp) {
        float mo[4];
        #pragma unroll
        for (int j = 0; j < 4; ++j) mo[j] = __shfl(m[qp], 4 * g + j);
        #pragma unroll
        for (int j = 0; j < 4; ++j) {
            const int q = 16 * qp + 4 * g + j;
            const float sc = fexp2(mo[j] - ML2m[q]);   // exp2(-inf)=0 for idle waves
            #pragma unroll
            for (int dt = 0; dt < 4; ++dt)
                Ow[q * 65 + 16 * dt + c] = o[qp][dt][j] * sc;
        }
    }
    __syncthreads();

    // ---- sum slots, normalize, write. Thread (w,c,g): d = 16(w&3)+c,
    // q = 16(w>>2) + 4g + j
    const int d = 16 * (w & 3) + c;
    const int qb = 16 * (w >> 2);
    #pragma unroll
    for (int j = 0; j < 4; ++j) {
        const int q = qb + 4 * g + j;
        float v = 0.f;
        #pragma unroll
        for (int s = 0; s < NW; ++s) v += Oslab[(size_t)s * (32 * 65) + q * 65 + d];
        out[((size_t)b * TN + (size_t)qt * 32 + q) * HN + d] = v / ML2l[q];
    }
}

// ---------------------------------------------------------------------------
extern "C" void kernel_launch(void* const* d_in, const int* in_sizes, int n_in,
                              void* d_out, int out_size, void* d_ws, size_t ws_size,
                              hipStream_t stream) {
    const float* emb = (const float*)d_in[0];
    const float* Wq  = (const float*)d_in[1];
    const float* Wk  = (const float*)d_in[2];
    const float* Wv  = (const float*)d_in[3];
    float* out = (float*)d_out;

    unsigned short* ws  = (unsigned short*)d_ws;
    unsigned short* W16 = ws;                                // [192][1024]   384 KB
    unsigned short* QK  = ws + 196608;                       // [2][BT][64]   4 MB
    unsigned short* VT  = ws + 196608 + 2 * (size_t)BT * HN; // [4][64][4096] 2 MB

    wconv<<<192, 256, 0, stream>>>(Wq, Wk, Wv, W16);
    qkv_gemm<<<BT / 64, 512, 0, stream>>>(emb, W16, QK, VT);
    attn<<<BN * (TN / 32), 512, 0, stream>>>(QK, VT, out);
}

// Round 8
// 144.774 us; speedup vs baseline: 1.1311x; 1.1311x over previous
//
#include <hip/hip_runtime.h>
#include <math.h>
#include <stdint.h>

#define BN 4
#define TN 4096
#define EN 1024
#define HN 64
#define BT (BN*TN)

typedef __attribute__((ext_vector_type(8))) short   short8;   // 8 bf16 MFMA frag
typedef __attribute__((ext_vector_type(4))) float   f32x4;    // MFMA acc
typedef __attribute__((ext_vector_type(4))) unsigned short us4;
typedef __attribute__((ext_vector_type(8))) unsigned short us8;

// fp32 -> bf16 RNE
__device__ __forceinline__ unsigned short f2b(float f) {
    union { float f; uint32_t u; } v; v.f = f;
    uint32_t u = v.u;
    return (unsigned short)((u + 0x7FFFu + ((u >> 16) & 1u)) >> 16);
}

__device__ __forceinline__ float fexp2(float x) {
#if __has_builtin(__builtin_amdgcn_exp2f)
    return __builtin_amdgcn_exp2f(x);
#else
    return exp2f(x);
#endif
}

// ---------------------------------------------------------------------------
// W -> bf16. Rows 0-63: Wq scaled by log2(e)/32 (softmax in exp2 domain).
// Rows 64-127: Wk. Rows 128-191: Wv.
// ---------------------------------------------------------------------------
__global__ __launch_bounds__(256)
void wconv(const float* __restrict__ Wq, const float* __restrict__ Wk,
           const float* __restrict__ Wv, unsigned short* __restrict__ W16) {
    const int row = blockIdx.x;
    const int t = threadIdx.x;
    const float* src;
    float sc = 1.0f;
    if (row < 64)       { src = Wq + (size_t)row * EN; sc = 0.045084220f; }
    else if (row < 128) { src = Wk + (size_t)(row - 64) * EN; }
    else                { src = Wv + (size_t)(row - 128) * EN; }
    float4 v = *(const float4*)(src + t * 4);
    us4 p;
    p[0] = f2b(v.x * sc); p[1] = f2b(v.y * sc);
    p[2] = f2b(v.z * sc); p[3] = f2b(v.w * sc);
    *(us4*)&W16[(size_t)row * EN + t * 4] = p;
}

// ---------------------------------------------------------------------------
// QKV projection GEMM: C[16384][192] = emb * W16^T, bf16 MFMA.
// M-tile 32 -> grid 512 (2 blocks/CU, 16 waves/CU). 512 threads = 8 waves
// (2M x 4N; 16 rows x 48 cols per wave). K-step 64, double-buffered LDS,
// 2-step-ahead register prefetch. Q,K written [wsel][r][d]; V transposed.
// ---------------------------------------------------------------------------
__global__ __launch_bounds__(512, 2)
void qkv_gemm(const float* __restrict__ emb, const unsigned short* __restrict__ W16,
              unsigned short* __restrict__ QK, unsigned short* __restrict__ VT) {
    __shared__ __align__(16) unsigned short A_lds[2][32][72];
    __shared__ __align__(16) unsigned short B_lds[2][192][72];

    const int tid = threadIdx.x;
    const int wid = tid >> 6, lane = tid & 63;
    const int c = lane & 15, g = lane >> 4;
    const int wm = wid & 1, wn = wid >> 1;          // 2M x 4N waves
    const int r0 = blockIdx.x * 32;

    const bool doA = (tid < 256);                   // A: 32 rows x 8 us8-chunks
    const int ar = tid >> 3, ach = tid & 7;
    const int br0 = tid >> 3,           bch0 = tid & 7;    // B: 1536 us8 slots
    const int br1 = (tid + 512) >> 3;
    const int br2 = (tid + 1024) >> 3;

    const f32x4 fzero = {0.f, 0.f, 0.f, 0.f};
    f32x4 acc[3];
    #pragma unroll
    for (int j = 0; j < 3; ++j) acc[j] = fzero;

    // two register prefetch banks
    float4 pa0[2], pa1[2];
    us8 pb0[2], pb1[2], pb2[2];

    // ---- prologue: issue loads for steps 0 and 1
    #pragma unroll
    for (int t = 0; t < 2; ++t) {
        const int k0 = t * 64;
        if (doA) {
            pa0[t] = *(const float4*)&emb[(size_t)(r0 + ar) * EN + k0 + ach * 8];
            pa1[t] = *(const float4*)&emb[(size_t)(r0 + ar) * EN + k0 + ach * 8 + 4];
        }
        pb0[t] = *(const us8*)&W16[(size_t)br0 * EN + k0 + bch0 * 8];
        pb1[t] = *(const us8*)&W16[(size_t)br1 * EN + k0 + bch0 * 8];
        pb2[t] = *(const us8*)&W16[(size_t)br2 * EN + k0 + bch0 * 8];
    }
    // write step 0 (bank 0) into LDS buf 0
    {
        if (doA) {
            us8 ap;
            ap[0] = f2b(pa0[0].x); ap[1] = f2b(pa0[0].y); ap[2] = f2b(pa0[0].z); ap[3] = f2b(pa0[0].w);
            ap[4] = f2b(pa1[0].x); ap[5] = f2b(pa1[0].y); ap[6] = f2b(pa1[0].z); ap[7] = f2b(pa1[0].w);
            *(us8*)&A_lds[0][ar][ach * 8] = ap;
        }
        *(us8*)&B_lds[0][br0][bch0 * 8] = pb0[0];
        *(us8*)&B_lds[0][br1][bch0 * 8] = pb1[0];
        *(us8*)&B_lds[0][br2][bch0 * 8] = pb2[0];
    }
    __syncthreads();

    #pragma unroll 2
    for (int t = 0; t < 16; ++t) {
        const int cur = t & 1;    // static after unroll-2
        // issue loads for step t+2 into bank[cur] (its old data already in LDS)
        if (t + 2 < 16) {
            const int kn = (t + 2) * 64;
            if (doA) {
                pa0[cur] = *(const float4*)&emb[(size_t)(r0 + ar) * EN + kn + ach * 8];
                pa1[cur] = *(const float4*)&emb[(size_t)(r0 + ar) * EN + kn + ach * 8 + 4];
            }
            pb0[cur] = *(const us8*)&W16[(size_t)br0 * EN + kn + bch0 * 8];
            pb1[cur] = *(const us8*)&W16[(size_t)br1 * EN + kn + bch0 * 8];
            pb2[cur] = *(const us8*)&W16[(size_t)br2 * EN + kn + bch0 * 8];
        }

        // compute from LDS[cur]
        short8 af[2], bf[3][2];
        #pragma unroll
        for (int ks = 0; ks < 2; ++ks)
            af[ks] = *(const short8*)&A_lds[cur][16 * wm + c][32 * ks + 8 * g];
        #pragma unroll
        for (int nt = 0; nt < 3; ++nt)
            #pragma unroll
            for (int ks = 0; ks < 2; ++ks)
                bf[nt][ks] = *(const short8*)&B_lds[cur][48 * wn + 16 * nt + c][32 * ks + 8 * g];
        #pragma unroll
        for (int ks = 0; ks < 2; ++ks)
            #pragma unroll
            for (int nt = 0; nt < 3; ++nt)
                acc[nt] = __builtin_amdgcn_mfma_f32_16x16x32_bf16(
                    af[ks], bf[nt][ks], acc[nt], 0, 0, 0);

        // write bank[(t+1)&1] (holding step t+1, issued one step ago) to LDS
        if (t + 1 < 16) {
            const int nb = cur ^ 1;
            if (doA) {
                us8 ap;
                ap[0] = f2b(pa0[nb].x); ap[1] = f2b(pa0[nb].y); ap[2] = f2b(pa0[nb].z); ap[3] = f2b(pa0[nb].w);
                ap[4] = f2b(pa1[nb].x); ap[5] = f2b(pa1[nb].y); ap[6] = f2b(pa1[nb].z); ap[7] = f2b(pa1[nb].w);
                *(us8*)&A_lds[nb][ar][ach * 8] = ap;
            }
            *(us8*)&B_lds[nb][br0][bch0 * 8] = pb0[nb];
            *(us8*)&B_lds[nb][br1][bch0 * 8] = pb1[nb];
            *(us8*)&B_lds[nb][br2][bch0 * 8] = pb2[nb];
        }
        __syncthreads();
    }

    // epilogue: D row = 4g+j (A side), col = c (B side)  [proven layout]
    #pragma unroll
    for (int nt = 0; nt < 3; ++nt) {
        const int n = 48 * wn + 16 * nt + c;
        const int wsel = n >> 6;
        const int d = n & 63;
        const int rbase = r0 + 16 * wm + 4 * g;
        if (wsel < 2) {
            #pragma unroll
            for (int j = 0; j < 4; ++j)
                QK[(size_t)wsel * BT * HN + (size_t)(rbase + j) * HN + d] =
                    f2b(acc[nt][j]);
        } else {
            const int bb = rbase >> 12;
            const int tt = rbase & 4095;
            us4 p;
            #pragma unroll
            for (int j = 0; j < 4; ++j) p[j] = f2b(acc[nt][j]);
            *(us4*)&VT[(size_t)bb * HN * TN + (size_t)d * TN + tt] = p;
        }
    }
}

// ---------------------------------------------------------------------------
// Flash attention, bf16 MFMA, causal. Q-tile 32, grid 512 (2 blocks/CU),
// 256 threads = 4 waves; wave w owns KV-tiles jt = w, w+4, ... independently
// (own LDS slot, NO barriers in main loop). K/V staged via REGISTER PREFETCH:
// next tile's 16 us8 global loads issue right after current tile's LDS
// writes, landing under the MFMA/softmax work. Merge (m,l,O) at end.
// ---------------------------------------------------------------------------
#define NW 4

__global__ __launch_bounds__(256, 2)
void attn(const unsigned short* __restrict__ QK,
          const unsigned short* __restrict__ VT, float* __restrict__ out) {
    __shared__ __align__(16) unsigned short KV[NW][2][64][72];  // per-wave K,V slots
    __shared__ __align__(16) float MLm[NW][32];
    __shared__ __align__(16) float MLl[NW][32];
    __shared__ __align__(16) float ML2m[32];
    __shared__ __align__(16) float ML2l[32];

    const int tid = threadIdx.x;
    const int w = tid >> 6, lane = tid & 63, c = lane & 15, g = lane >> 4;
    const int bid = blockIdx.x;
    const int b = bid & 3;
    const int qt = (TN / 32 - 1) - (bid >> 2);   // heavy q-tiles first

    const unsigned short* Qg = QK + ((size_t)b * TN + (size_t)qt * 32) * HN;
    const unsigned short* Kg = QK + (size_t)BT * HN + (size_t)b * TN * HN;
    const unsigned short* Vg = VT + (size_t)b * HN * TN;

    unsigned short* Ks = &KV[w][0][0][0];
    unsigned short* Vs = &KV[w][1][0][0];

    // Q fragments straight from global (L2/L3-resident)
    short8 bq[2][2];
    #pragma unroll
    for (int ct = 0; ct < 2; ++ct)
        #pragma unroll
        for (int ks = 0; ks < 2; ++ks)
            bq[ct][ks] = *(const short8*)&Qg[(size_t)(16 * ct + c) * HN + 32 * ks + 8 * g];

    const f32x4 fzero = {0.f, 0.f, 0.f, 0.f};
    f32x4 o[2][4];
    #pragma unroll
    for (int i = 0; i < 2; ++i)
        #pragma unroll
        for (int j = 0; j < 4; ++j) o[i][j] = fzero;
    float m[2] = {-INFINITY, -INFINITY};
    float l[2] = {0.f, 0.f};

    const int jmax = qt >> 1;
    const int sr = lane >> 3, sc8 = lane & 7;    // staging map: 8 rows x 8 chunks

    // ---- prologue: load first KV tile into registers
    us8 kreg[8], vreg[8];
    if (w <= jmax) {
        #pragma unroll
        for (int i = 0; i < 8; ++i) {
            kreg[i] = *(const us8*)&Kg[((size_t)w * 64 + sr + 8 * i) * HN + sc8 * 8];
            vreg[i] = *(const us8*)&Vg[(size_t)(sr + 8 * i) * TN + w * 64 + sc8 * 8];
        }
    }

    for (int jt = w; jt <= jmax; jt += NW) {
        // ---- 1. staged regs -> this wave's LDS slot (wave-local, no barrier)
        #pragma unroll
        for (int i = 0; i < 8; ++i) {
            *(us8*)&Ks[(sr + 8 * i) * 72 + sc8 * 8] = kreg[i];
            *(us8*)&Vs[(sr + 8 * i) * 72 + sc8 * 8] = vreg[i];
        }
        // ---- 2. issue prefetch for jt+NW (lands under MFMA/softmax below)
        if (jt + NW <= jmax) {
            const int jn = jt + NW;
            #pragma unroll
            for (int i = 0; i < 8; ++i) {
                kreg[i] = *(const us8*)&Kg[((size_t)jn * 64 + sr + 8 * i) * HN + sc8 * 8];
                vreg[i] = *(const us8*)&Vg[(size_t)(sr + 8 * i) * TN + jn * 64 + sc8 * 8];
            }
        }

        // ---- 3. S^T[64k][32q] = K . Q^T
        f32x4 st[4][2];
        #pragma unroll
        for (int kt = 0; kt < 4; ++kt)
            #pragma unroll
            for (int ct = 0; ct < 2; ++ct) st[kt][ct] = fzero;
        #pragma unroll
        for (int kt = 0; kt < 4; ++kt) {
            #pragma unroll
            for (int ks = 0; ks < 2; ++ks) {
                short8 ak = *(const short8*)&Ks[(16 * kt + c) * 72 + 32 * ks + 8 * g];
                #pragma unroll
                for (int ct = 0; ct < 2; ++ct)
                    st[kt][ct] = __builtin_amdgcn_mfma_f32_16x16x32_bf16(
                        ak, bq[ct][ks], st[kt][ct], 0, 0, 0);
            }
        }

        // ---- causal mask (only the last tile crosses the diagonal)
        if (jt == jmax) {
            const int koff = jt * 64 - qt * 32;
            #pragma unroll
            for (int kt = 0; kt < 4; ++kt)
                #pragma unroll
                for (int ct = 0; ct < 2; ++ct)
                    #pragma unroll
                    for (int j = 0; j < 4; ++j)
                        if (16 * kt + 4 * g + j + koff > 16 * ct + c)
                            st[kt][ct][j] = -INFINITY;
        }

        // ---- 4. online softmax (exp2 domain), per q = 16ct + c
        #pragma unroll
        for (int ct = 0; ct < 2; ++ct) {
            float pmax = -INFINITY;
            #pragma unroll
            for (int kt = 0; kt < 4; ++kt)
                #pragma unroll
                for (int j = 0; j < 4; ++j) pmax = fmaxf(pmax, st[kt][ct][j]);
            pmax = fmaxf(pmax, __shfl_xor(pmax, 16));
            pmax = fmaxf(pmax, __shfl_xor(pmax, 32));
            const float mn = fmaxf(m[ct], pmax);
            const float alpha = fexp2(m[ct] - mn);
            float ls = 0.f;
            #pragma unroll
            for (int kt = 0; kt < 4; ++kt)
                #pragma unroll
                for (int j = 0; j < 4; ++j) {
                    float p = fexp2(st[kt][ct][j] - mn);
                    st[kt][ct][j] = p;
                    ls += p;
                }
            ls += __shfl_xor(ls, 16);
            ls += __shfl_xor(ls, 32);
            l[ct] = l[ct] * alpha + ls;
            m[ct] = mn;

            float a4[4];
            #pragma unroll
            for (int j = 0; j < 4; ++j) a4[j] = __shfl(alpha, 4 * g + j);
            #pragma unroll
            for (int dt = 0; dt < 4; ++dt)
                #pragma unroll
                for (int j = 0; j < 4; ++j) o[ct][dt][j] *= a4[j];
        }

        // ---- 5. write P[32q][64k] bf16 into the K slot (wave-local alias)
        #pragma unroll
        for (int kt = 0; kt < 4; ++kt)
            #pragma unroll
            for (int ct = 0; ct < 2; ++ct) {
                us4 p;
                #pragma unroll
                for (int j = 0; j < 4; ++j) p[j] = f2b(st[kt][ct][j]);
                *(us4*)&Ks[(16 * ct + c) * 72 + 16 * kt + 4 * g] = p;
            }

        // ---- 6. O += P . V
        #pragma unroll
        for (int ks = 0; ks < 2; ++ks) {
            short8 pa[2];
            #pragma unroll
            for (int qp = 0; qp < 2; ++qp)
                pa[qp] = *(const short8*)&Ks[(16 * qp + c) * 72 + 32 * ks + 8 * g];
            #pragma unroll
            for (int dt = 0; dt < 4; ++dt) {
                short8 bv = *(const short8*)&Vs[(16 * dt + c) * 72 + 32 * ks + 8 * g];
                #pragma unroll
                for (int qp = 0; qp < 2; ++qp)
                    o[qp][dt] = __builtin_amdgcn_mfma_f32_16x16x32_bf16(
                        pa[qp], bv, o[qp][dt], 0, 0, 0);
            }
        }
    }

    // ---- publish per-wave m,l
    if (g == 0) {
        MLm[w][c]      = m[0];  MLl[w][c]      = l[0];
        MLm[w][c + 16] = m[1];  MLl[w][c + 16] = l[1];
    }
    __syncthreads();

    // ---- combine m,l across waves (first 32 threads)
    if (tid < 32) {
        const int q = tid;
        float M = MLm[0][q];
        #pragma unroll
        for (int s = 1; s < NW; ++s) M = fmaxf(M, MLm[s][q]);
        float L = 0.f;
        #pragma unroll
        for (int s = 0; s < NW; ++s) L += MLl[s][q] * fexp2(MLm[s][q] - M);
        ML2m[q] = M;
        ML2l[q] = L;
    }
    __syncthreads();   // all waves past main loop before Oslab aliasing

    // ---- scale own O and dump to per-wave f32 slot (reuse KV memory)
    float* Oslab = (float*)&KV[0][0][0][0];
    float* Ow = Oslab + (size_t)w * (32 * 65);
    #pragma unroll
    for (int qp = 0; qp < 2; ++qp) {
        float mo[4];
        #pragma unroll
        for (int j = 0; j < 4; ++j) mo[j] = __shfl(m[qp], 4 * g + j);
        #pragma unroll
        for (int j = 0; j < 4; ++j) {
            const int q = 16 * qp + 4 * g + j;
            const float sc = fexp2(mo[j] - ML2m[q]);   // exp2(-inf)=0 for idle waves
            #pragma unroll
            for (int dt = 0; dt < 4; ++dt)
                Ow[q * 65 + 16 * dt + c] = o[qp][dt][j] * sc;
        }
    }
    __syncthreads();

    // ---- sum slots, normalize, write out. Wave w owns d-slice [16w,16w+16)
    const int d = 16 * w + c;
    #pragma unroll
    for (int tq = 0; tq < 8; ++tq) {
        const int q = 4 * tq + g;
        float v = 0.f;
        #pragma unroll
        for (int s = 0; s < NW; ++s) v += Oslab[(size_t)s * (32 * 65) + q * 65 + d];
        out[((size_t)b * TN + (size_t)qt * 32 + q) * HN + d] = v / ML2l[q];
    }
}

// ---------------------------------------------------------------------------
extern "C" void kernel_launch(void* const* d_in, const int* in_sizes, int n_in,
                              void* d_out, int out_size, void* d_ws, size_t ws_size,
                              hipStream_t stream) {
    const float* emb = (const float*)d_in[0];
    const float* Wq  = (const float*)d_in[1];
    const float* Wk  = (const float*)d_in[2];
    const float* Wv  = (const float*)d_in[3];
    float* out = (float*)d_out;

    unsigned short* ws  = (unsigned short*)d_ws;
    unsigned short* W16 = ws;                                // [192][1024]   384 KB
    unsigned short* QK  = ws + 196608;                       // [2][BT][64]   4 MB
    unsigned short* VT  = ws + 196608 + 2 * (size_t)BT * HN; // [4][64][4096] 2 MB

    wconv<<<192, 256, 0, stream>>>(Wq, Wk, Wv, W16);
    qkv_gemm<<<BT / 32, 512, 0, stream>>>(emb, W16, QK, VT);
    attn<<<BN * (TN / 32), 256, 0, stream>>>(QK, VT, out);
}